// Round 4
// baseline (570.085 us; speedup 1.0000x reference)
//
#include <hip/hip_runtime.h>
#include <stdint.h>

#define N_PTS 524288
#define DQ 64
#define HQ 256
#define WQ 256
#define MAP_BYTES (2*DQ*HQ*WQ*4)   /* 33554432 */
#define NBKT 4096                  /* buckets = mbase >> 11 */

typedef short bf8  __attribute__((ext_vector_type(8)));
typedef float f16v __attribute__((ext_vector_type(16)));

static __device__ __forceinline__ short f2bf(float f) {
    union { float f; uint32_t u; } v; v.f = f;
    return (short)((v.u + 0x7fffu + ((v.u >> 16) & 1u)) >> 16);
}
static __device__ __forceinline__ float fast_sigmoid(float x) {
    return 1.f / (1.f + __expf(-x));
}
static __device__ __forceinline__ float fast_tanh(float x) {
    return 1.f - 2.f / (__expf(2.f * x) + 1.f);
}

// ---- spatial counting sort: histogram over linearized coordinate ----
__global__ void k_hist(const int* __restrict__ coors, int* __restrict__ hist) {
    int n = blockIdx.x * 256 + threadIdx.x;
    int4 c = ((const int4*)coors)[n];
    int mbase = ((c.x*DQ + c.y)*HQ + c.z)*WQ + c.w;
    atomicAdd(&hist[mbase >> 11], 1);
}

// single-block exclusive prefix sum over NBKT counts (in place)
__global__ void k_scan(int* __restrict__ hist) {
    __shared__ int wsum[4];
    int tid = threadIdx.x;
    int lane = tid & 63, wv = tid >> 6;
    int v[16]; int s = 0;
    #pragma unroll
    for (int i = 0; i < 16; i++) { v[i] = hist[tid*16 + i]; s += v[i]; }
    int sc = s;
    #pragma unroll
    for (int d = 1; d < 64; d <<= 1) {
        int t = __shfl_up(sc, d, 64);
        if (lane >= d) sc += t;
    }
    if (lane == 63) wsum[wv] = sc;
    __syncthreads();
    int base = 0;
    #pragma unroll
    for (int w = 0; w < 4; w++) if (w < wv) base += wsum[w];
    int excl = base + sc - s;
    #pragma unroll
    for (int i = 0; i < 16; i++) { int c = v[i]; hist[tid*16 + i] = excl; excl += c; }
}

// fused: rank assignment + bf16 feature pack into SORTED slot + map/sorg scatter
__global__ void k_feats(const float* __restrict__ xf, const float* __restrict__ hf,
                        const int* __restrict__ coors, int* __restrict__ hist,
                        short* __restrict__ fb, int* __restrict__ map,
                        int* __restrict__ sorg) {
    int t = blockIdx.x * 256 + threadIdx.x;           // t < N*8
    int n = t >> 3, seg = t & 7;
    int lane = threadIdx.x & 63;
    int slot = 0;
    if (seg == 0) {
        int4 c = ((const int4*)coors)[n];
        int mb = ((c.x*DQ + c.y)*HQ + c.z)*WQ + c.w;
        slot = atomicAdd(&hist[mb >> 11], 1);
        map[mb] = slot;                               // map stores SORTED slot
        sorg[slot] = n;
    }
    slot = __shfl(slot, lane & 56, 64);               // broadcast from seg==0 lane
    const float* src = (seg < 4) ? (xf + n*32 + seg*8) : (hf + n*32 + seg*8 - 32);
    float4 a = ((const float4*)src)[0];
    float4 b = ((const float4*)src)[1];
    bf8 rv;
    rv[0]=f2bf(a.x); rv[1]=f2bf(a.y); rv[2]=f2bf(a.z); rv[3]=f2bf(a.w);
    rv[4]=f2bf(b.x); rv[5]=f2bf(b.y); rv[6]=f2bf(b.z); rv[7]=f2bf(b.w);
    ((bf8*)fb)[slot*8 + seg] = rv;                    // fb in sorted order
}

__global__ void k_wt(const float* __restrict__ w, short* __restrict__ wt) {
    int t = blockIdx.x * 256 + threadIdx.x;
    if (t >= 27*64*128) return;
    int jj = t & 7, c = (t >> 3) & 127, jg = (t >> 10) & 7, k = t >> 13;
    int j = jg*8 + jj;
    wt[t] = f2bf(w[(k*64 + j)*128 + c]);              // Wt[k][jg][c][jj] = W[k][j][c]
}

__launch_bounds__(256, 3)
__global__ void k_main(const int* __restrict__ map, const short* __restrict__ fb,
                       const short* __restrict__ wt, const float* __restrict__ bias,
                       const float* __restrict__ cfeat, const int* __restrict__ coors,
                       const int* __restrict__ sorg, const short* __restrict__ zp,
                       float* __restrict__ out)
{
    __shared__ short Wlds[2][8192];   // double-buffered W slice: 2 x 16 kB

    const int tid  = threadIdx.x;
    const int lane = tid & 63;
    const int wv   = tid >> 6;
    const int l31  = lane & 31;
    const int lhi  = lane >> 5;

    // chunked XCD swizzle: 4096 blocks = 8 XCDs x 512 contiguous
    const int bid   = (blockIdx.x & 7) * 512 + (blockIdx.x >> 3);
    const int pw    = bid * 128 + wv * 32;        // this wave's 32-point base (sorted order)

    const int orig = sorg[pw + l31];              // lanes 0-31 own points; 32-63 duplicate
    const int4 cr = ((const int4*)coors)[orig];   // b,z,y,x

    // dual-offset probe: lane (l31,lhi) probes offset (o+lhi) for point l31.
    // Branch-free (clamp+select): exactly ONE vmem load always -> exact vmcnt.
    auto probe2 = [&](int o) -> int {
        int oo = o + lhi;
        int dz = oo/9 - 1, dy = (oo/3)%3 - 1, dxo = oo%3 - 1;
        int nz = cr.y + dz, ny = cr.z + dy, nx = cr.w + dxo;
        bool inb = ((unsigned)nz < (unsigned)DQ) & ((unsigned)ny < (unsigned)HQ) &
                   ((unsigned)nx < (unsigned)WQ);
        int cz = min(max(nz, 0), DQ-1);
        int cy = min(max(ny, 0), HQ-1);
        int cx = min(max(nx, 0), WQ-1);
        int nid = map[((cr.x*DQ + cz)*HQ + cy)*WQ + cx];
        return inb ? nid : -1;
    };

    // async stage of W[ko] (16 kB) into Wlds[ko&1]; exactly 4 vmem ops per wave
    auto stageW = [&](int ko) {
        const short* src = wt + ko*8192;
        #pragma unroll
        for (int i = 0; i < 4; i++) {
            int cb = i*256 + wv*64;          // 16B-chunk base for this wave
            __builtin_amdgcn_global_load_lds(
                (const __attribute__((address_space(1))) void*)(src + (size_t)(cb + lane)*8),
                (__attribute__((address_space(3))) void*)&Wlds[ko & 1][cb*8],
                16, 0, 0);
        }
    };

    // register gather of this lane's A fragments; exactly 4 vmem ops (pointer select)
    auto gather = [&](int n0, bf8* dst) {
        const short* s0 = (n0 >= 0) ? (fb + (size_t)n0*64 + lhi*8) : (zp + lhi*8);
        #pragma unroll
        for (int ks = 0; ks < 4; ks++) dst[ks] = *(const bf8*)(s0 + ks*16);
    };

    f16v acc[4];
    #pragma unroll
    for (int ct = 0; ct < 4; ct++) {
        float bv = bias[ct*32 + l31];
        #pragma unroll
        for (int r = 0; r < 16; r++) acc[ct][r] = bv;
    }

    // ---- prologue: W(0); probe pairs (0,1),(2,3),(3,4); first gather; full drain ----
    stageW(0);
    int pr01 = probe2(0);
    int prm2 = probe2(2);    // covers offsets 2,3 -> half0 used at end of iter 0
    int prm1 = probe2(3);    // covers offsets 3,4 -> half0 used at end of iter 1

    bf8 a_cur[4], a_next[4];
    gather(__shfl(pr01, l31, 64), a_cur);         // offset 0
    int g0n = __shfl(pr01, l31 + 32, 64);         // offset 1 (next gather)

    __builtin_amdgcn_sched_barrier(0);
    asm volatile("s_waitcnt vmcnt(0)" ::: "memory");
    __builtin_amdgcn_s_barrier();
    __builtin_amdgcn_sched_barrier(0);

    #pragma unroll 1
    for (int ko = 0; ko < 27; ko++) {
        int pr0 = 0;
        // uniform vmem budget per iter (ko<26): 4 stage + 4 gather + 1 probe
        if (ko < 26) {
            stageW(ko + 1);
            __builtin_amdgcn_sched_barrier(0);
            gather(g0n, a_next);                  // offset ko+1, used next iter
            __builtin_amdgcn_sched_barrier(0);
            pr0 = probe2(ko + 4);                 // offsets ko+4,ko+5 (dummy if >26: unused)
        }

        // ---- MFMA phase: a from regs, b from LDS buf (staged LAST iter, fenced) ----
        const int buf = ko & 1;
        #pragma unroll
        for (int ks = 0; ks < 4; ks++) {
            int jg = ks*2 + lhi;
            const short* wb = &Wlds[buf][(jg*128 + l31)*8];
            #pragma unroll
            for (int ct = 0; ct < 4; ct++) {
                bf8 b = *(const bf8*)(wb + ct*32*8);
                acc[ct] = __builtin_amdgcn_mfma_f32_32x32x16_bf16(a_cur[ks], b, acc[ct], 0, 0, 0);
            }
        }

        if (ko < 25) g0n = __shfl(prm2, l31, 64); // offset ko+2 (half0 of probe from iter ko-2)
        prm2 = prm1; prm1 = pr0;
        #pragma unroll
        for (int j = 0; j < 4; j++) a_cur[j] = a_next[j];

        // counted wait: only the 4 stage DMAs (oldest) must land before the barrier;
        // this iter's gather(4)+probe(1) stay in flight across it.
        if (ko < 26) {
            __builtin_amdgcn_sched_barrier(0);
            asm volatile("s_waitcnt vmcnt(5)" ::: "memory");
            __builtin_amdgcn_s_barrier();
            __builtin_amdgcn_sched_barrier(0);
        }
    }

    // ---- epilogue: LSTM gates; orig ids via shfl of already-loaded sorg values ----
    #pragma unroll
    for (int r = 0; r < 16; r++) {
        int row = (r & 3) + 8*(r >> 2) + 4*lhi;
        int opp = __shfl(orig, row, 64);          // sorg[pw+row], no reload
        float gi = acc[0][r];
        float gf = acc[1][r];
        float go = acc[2][r];
        float gg = acc[3][r];
        float cv = cfeat[opp*32 + l31];
        float si = fast_sigmoid(gi);
        float sf = fast_sigmoid(gf);
        float so = fast_sigmoid(go);
        float tg = fast_tanh(gg);
        float cn = sf*cv + si*tg;
        float hn = so * fast_tanh(cn);
        out[opp*32 + l31] = hn;
        out[N_PTS*32 + opp*32 + l31] = cn;
    }
}

extern "C" void kernel_launch(void* const* d_in, const int* in_sizes, int n_in,
                              void* d_out, int out_size, void* d_ws, size_t ws_size,
                              hipStream_t stream) {
    const float* xf    = (const float*)d_in[0];
    const float* hf    = (const float*)d_in[1];
    const float* cf    = (const float*)d_in[2];
    const float* w     = (const float*)d_in[3];
    const float* bias  = (const float*)d_in[4];
    const int*   coors = (const int*)d_in[5];
    float* out = (float*)d_out;

    char* base = (char*)d_ws;
    int*   map    = (int*)base;                                        // 33554432 B
    short* fb     = (short*)(base + MAP_BYTES);                        // 67108864 B
    short* wtb    = (short*)(base + 100663296);                        //   442368 B
    short* zp     = (short*)(base + 101105664);                        //      512 B
    int*   sorg   = (int*)(base + 101106176);                          //  2097152 B
    int*   hist   = (int*)(base + 103203328);                          //    16384 B

    hipMemsetAsync(map, 0xFF, MAP_BYTES, stream);                      // map = -1
    hipMemsetAsync(hist, 0, NBKT*4, stream);
    hipMemsetAsync(zp, 0, 256, stream);                                // zero row
    k_hist<<<N_PTS/256, 256, 0, stream>>>(coors, hist);
    k_scan<<<1, 256, 0, stream>>>(hist);
    k_feats<<<(N_PTS*8)/256, 256, 0, stream>>>(xf, hf, coors, hist, fb, map, sorg);
    k_wt<<<(27*64*128 + 255)/256, 256, 0, stream>>>(w, wtb);
    k_main<<<N_PTS/128, 256, 0, stream>>>(map, fb, wtb, bias, cf, coors, sorg, zp, out);
}

// Round 5
// 524.056 us; speedup vs baseline: 1.0878x; 1.0878x over previous
//
#include <hip/hip_runtime.h>
#include <stdint.h>

#define N_PTS 524288
#define DQ 64
#define HQ 256
#define WQ 256
#define MAP_BYTES (2*DQ*HQ*WQ*4)   /* 33554432 */
#define FEAT_BLOCKS ((N_PTS*8)/256)      /* 16384 */
#define WT_BLOCKS   ((27*64*128 + 255)/256)  /* 864 */

typedef short bf8  __attribute__((ext_vector_type(8)));
typedef float f16v __attribute__((ext_vector_type(16)));

static __device__ __forceinline__ short f2bf(float f) {
    union { float f; uint32_t u; } v; v.f = f;
    return (short)((v.u + 0x7fffu + ((v.u >> 16) & 1u)) >> 16);
}
static __device__ __forceinline__ float fast_sigmoid(float x) {
    return 1.f / (1.f + __expf(-x));
}
static __device__ __forceinline__ float fast_tanh(float x) {
    return 1.f - 2.f / (__expf(2.f * x) + 1.f);
}

// fused prep: bf16 feature pack (original order, fully coalesced) + map scatter
//             + weight transform + zp clear.  One dispatch.
__global__ void k_prep(const float* __restrict__ xf, const float* __restrict__ hf,
                       const int* __restrict__ coors, const float* __restrict__ w,
                       short* __restrict__ fb, int* __restrict__ map,
                       short* __restrict__ wt, short* __restrict__ zp) {
    int b = blockIdx.x;
    if (b < FEAT_BLOCKS) {
        int t = b * 256 + threadIdx.x;                // t < N*8
        int n = t >> 3, seg = t & 7;
        const float* src = (seg < 4) ? (xf + n*32 + seg*8) : (hf + n*32 + seg*8 - 32);
        float4 a = ((const float4*)src)[0];
        float4 bb = ((const float4*)src)[1];
        bf8 rv;
        rv[0]=f2bf(a.x); rv[1]=f2bf(a.y); rv[2]=f2bf(a.z); rv[3]=f2bf(a.w);
        rv[4]=f2bf(bb.x); rv[5]=f2bf(bb.y); rv[6]=f2bf(bb.z); rv[7]=f2bf(bb.w);
        ((bf8*)fb)[t] = rv;                           // coalesced 16B/lane
        if (seg == 0) {
            int4 c = ((const int4*)coors)[n];
            map[((c.x*DQ + c.y)*HQ + c.z)*WQ + c.w] = n;   // map stores point id
        }
    } else {
        int t = (b - FEAT_BLOCKS) * 256 + threadIdx.x;
        if (t < 27*64*128) {
            int jj = t & 7, c = (t >> 3) & 127, jg = (t >> 10) & 7, k = t >> 13;
            int j = jg*8 + jj;
            wt[t] = f2bf(w[(k*64 + j)*128 + c]);      // Wt[k][jg][c][jj] = W[k][j][c]
        }
        if (b == FEAT_BLOCKS + WT_BLOCKS - 1 && threadIdx.x < 32)
            ((int4*)zp)[threadIdx.x] = int4{0,0,0,0}; // 512 B zero row
    }
}

__launch_bounds__(256, 2)
__global__ void k_main(const int* __restrict__ map, const short* __restrict__ fb,
                       const short* __restrict__ wt, const float* __restrict__ bias,
                       const float* __restrict__ cfeat, const int* __restrict__ coors,
                       const short* __restrict__ zp, float* __restrict__ out)
{
    __shared__ short Wlds[2][8192];   // double-buffered W slice: 2 x 16 kB

    const int tid  = threadIdx.x;
    const int lane = tid & 63;
    const int wv   = tid >> 6;
    const int l31  = lane & 31;
    const int lhi  = lane >> 5;

    const int pbase = blockIdx.x * 256;
    const int p     = pbase + wv*64 + lane;

    const int4 cr = ((const int4*)coors)[p];   // b,z,y,x
    const int mb0 = cr.x*DQ;

    // branch-free probe (clamp+select): exactly ONE vmem load per call -> exact vmcnt
    auto probe = [&](int ko) -> int {
        int dz = ko/9 - 1, dy = (ko/3)%3 - 1, dxo = ko%3 - 1;
        int nz = cr.y + dz, ny = cr.z + dy, nx = cr.w + dxo;
        bool inb = ((unsigned)nz < (unsigned)DQ) & ((unsigned)ny < (unsigned)HQ) &
                   ((unsigned)nx < (unsigned)WQ);
        int cz = min(max(nz, 0), DQ-1);
        int cy = min(max(ny, 0), HQ-1);
        int cx = min(max(nx, 0), WQ-1);
        int nid = map[((mb0 + cz)*HQ + cy)*WQ + cx];
        return inb ? nid : -1;
    };

    // async stage of W[ko] (16 kB) into Wlds[ko&1]; exactly 4 vmem ops per wave
    auto stageW = [&](int ko) {
        const short* src = wt + ko*8192;
        #pragma unroll
        for (int i = 0; i < 4; i++) {
            int cb = i*256 + wv*64;          // 16B-chunk base for this wave
            __builtin_amdgcn_global_load_lds(
                (const __attribute__((address_space(1))) void*)(src + (size_t)(cb + lane)*8),
                (__attribute__((address_space(3))) void*)&Wlds[ko & 1][cb*8],
                16, 0, 0);
        }
    };

    // register gather of A fragments; exactly 8 vmem ops (pointer select, no branch)
    auto gather = [&](int n0, int n1, bf8* dst) {
        const short* s0 = (n0 >= 0) ? (fb + (size_t)n0*64 + lhi*8) : (zp + lhi*8);
        const short* s1 = (n1 >= 0) ? (fb + (size_t)n1*64 + lhi*8) : (zp + lhi*8);
        #pragma unroll
        for (int j = 0; j < 4; j++) {
            dst[j]     = *(const bf8*)(s0 + j*16);
            dst[4 + j] = *(const bf8*)(s1 + j*16);
        }
    };

    f16v acc[2][4];
    #pragma unroll
    for (int mt = 0; mt < 2; mt++)
        #pragma unroll
        for (int ct = 0; ct < 4; ct++) {
            float bv = bias[ct*32 + l31];
            #pragma unroll
            for (int r = 0; r < 16; r++) acc[mt][ct][r] = bv;
        }

    // ---- prologue: W(0), probes, first gather into fA; one full drain ----
    stageW(0);
    int pA = probe(0);
    int pB = probe(1);
    int pr_old = probe(2);

    bf8 fA[8], fB[8];
    {
        int g0 = __shfl(pA, l31, 64);
        int g1 = __shfl(pA, l31 + 32, 64);
        gather(g0, g1, fA);
    }
    int g0n = __shfl(pB, l31, 64);
    int g1n = __shfl(pB, l31 + 32, 64);

    __builtin_amdgcn_sched_barrier(0);
    asm volatile("s_waitcnt vmcnt(0)" ::: "memory");
    __builtin_amdgcn_s_barrier();
    __builtin_amdgcn_sched_barrier(0);

    // One iteration: MFMA consumes FA (gathered LAST iter -> full-iter latency cover);
    // gathers fill FB for the NEXT iter.  No register copies (ping-pong by name).
#define ITER_BODY(KO, FA, FB)                                                     \
    {                                                                             \
        const int _ko = (KO);                                                     \
        if (_ko < 26) {                                                           \
            stageW(_ko + 1);                   /* 4 vmem, oldest this iter */     \
            __builtin_amdgcn_sched_barrier(0);                                    \
            gather(g0n, g1n, FB);              /* 8 vmem, consumed next iter */   \
            __builtin_amdgcn_sched_barrier(0);                                    \
        }                                                                         \
        int pr_new = (_ko < 24) ? probe(_ko + 3) : -1;   /* 1 vmem */             \
        const int buf = _ko & 1;                                                  \
        _Pragma("unroll")                                                         \
        for (int ks = 0; ks < 4; ks++) {                                          \
            int jg = ks*2 + lhi;                                                  \
            const short* wb = &Wlds[buf][(jg*128 + l31)*8];                       \
            _Pragma("unroll")                                                     \
            for (int ct = 0; ct < 4; ct++) {                                      \
                bf8 b = *(const bf8*)(wb + ct*32*8);                              \
                acc[0][ct] = __builtin_amdgcn_mfma_f32_32x32x16_bf16(FA[ks],     b, acc[0][ct], 0, 0, 0); \
                acc[1][ct] = __builtin_amdgcn_mfma_f32_32x32x16_bf16(FA[4 + ks], b, acc[1][ct], 0, 0, 0); \
            }                                                                     \
        }                                                                         \
        if (_ko < 25) {                        /* nids for data (ko+2) */         \
            g0n = __shfl(pr_old, l31, 64);                                        \
            g1n = __shfl(pr_old, l31 + 32, 64);                                   \
            pr_old = pr_new;                                                      \
        }                                                                         \
        if (_ko < 26) {                                                           \
            __builtin_amdgcn_sched_barrier(0);                                    \
            /* counted wait: only the 4 stage DMAs must land; gathers+probe fly */\
            if (_ko < 24) { asm volatile("s_waitcnt vmcnt(9)" ::: "memory"); }    \
            else          { asm volatile("s_waitcnt vmcnt(8)" ::: "memory"); }    \
            __builtin_amdgcn_s_barrier();                                         \
            __builtin_amdgcn_sched_barrier(0);                                    \
        }                                                                         \
    }

    #pragma unroll 1
    for (int ko = 0; ko < 26; ko += 2) {
        ITER_BODY(ko,     fA, fB)
        ITER_BODY(ko + 1, fB, fA)
    }
    ITER_BODY(26, fA, fB)
#undef ITER_BODY

    // ---- epilogue: LSTM gates, lane-local; original order -> coalesced ----
    #pragma unroll
    for (int mt = 0; mt < 2; mt++) {
        #pragma unroll
        for (int r = 0; r < 16; r++) {
            int row = (r & 3) + 8*(r >> 2) + 4*lhi;
            int pp  = pbase + wv*64 + mt*32 + row;
            float gi = acc[mt][0][r];
            float gf = acc[mt][1][r];
            float go = acc[mt][2][r];
            float gg = acc[mt][3][r];
            float cv = cfeat[pp*32 + l31];
            float si = fast_sigmoid(gi);
            float sf = fast_sigmoid(gf);
            float so = fast_sigmoid(go);
            float tg = fast_tanh(gg);
            float cn = sf*cv + si*tg;
            float hn = so * fast_tanh(cn);
            out[pp*32 + l31] = hn;
            out[N_PTS*32 + pp*32 + l31] = cn;
        }
    }
}

extern "C" void kernel_launch(void* const* d_in, const int* in_sizes, int n_in,
                              void* d_out, int out_size, void* d_ws, size_t ws_size,
                              hipStream_t stream) {
    const float* xf    = (const float*)d_in[0];
    const float* hf    = (const float*)d_in[1];
    const float* cf    = (const float*)d_in[2];
    const float* w     = (const float*)d_in[3];
    const float* bias  = (const float*)d_in[4];
    const int*   coors = (const int*)d_in[5];
    float* out = (float*)d_out;

    char* base = (char*)d_ws;
    int*   map    = (int*)base;                                        // 33554432 B
    short* fb     = (short*)(base + MAP_BYTES);                        // 67108864 B
    short* wtb    = (short*)(base + 100663296);                        //   442368 B
    short* zp     = (short*)(base + 101105664);                        //      512 B

    hipMemsetAsync(map, 0xFF, MAP_BYTES, stream);                      // map = -1
    k_prep<<<FEAT_BLOCKS + WT_BLOCKS, 256, 0, stream>>>(xf, hf, coors, w, fb, map, wtb, zp);
    k_main<<<N_PTS/256, 256, 0, stream>>>(map, fb, wtb, bias, cf, coors, zp, out);
}

// Round 6
// 521.968 us; speedup vs baseline: 1.0922x; 1.0040x over previous
//
#include <hip/hip_runtime.h>
#include <stdint.h>

#define N_PTS 524288
#define DQ 64
#define HQ 256
#define WQ 256
/* halo map: [B=2][66][258][258] ints, memset 0; value = point_id + 1 (0 = empty) */
#define MD 66
#define MH 258
#define MW 258
#define MAP_INTS (2*MD*MH*MW)            /* 8,786,448 */
#define MAP_PAD  35145856                /* MAP_INTS*4 = 35,145,792 padded to 128 */
#define FEAT_BLOCKS ((N_PTS*8)/256)      /* 16384 */
#define WT_BLOCKS   ((27*64*128 + 255)/256)  /* 864 */

typedef short bf8  __attribute__((ext_vector_type(8)));
typedef float f16v __attribute__((ext_vector_type(16)));

/* linearized neighbor offsets in the halo map, (dz*MH + dy)*MW + dx */
static __device__ const int DOFF[27] = {
    -66823, -66822, -66821, -66565, -66564, -66563, -66307, -66306, -66305,
      -259,   -258,   -257,     -1,      0,      1,    257,    258,    259,
     66305,  66306,  66307,  66563,  66564,  66565,  66821,  66822,  66823
};

static __device__ __forceinline__ short f2bf(float f) {
    union { float f; uint32_t u; } v; v.f = f;
    return (short)((v.u + 0x7fffu + ((v.u >> 16) & 1u)) >> 16);
}
static __device__ __forceinline__ float fast_sigmoid(float x) {
    return 1.f / (1.f + __expf(-x));
}
static __device__ __forceinline__ float fast_tanh(float x) {
    return 1.f - 2.f / (__expf(2.f * x) + 1.f);
}

// fused prep: bf16 feature pack (row n+1; row 0 stays zero) + halo-map scatter
//             + weight transform.  One dispatch.
__global__ void k_prep(const float* __restrict__ xf, const float* __restrict__ hf,
                       const int* __restrict__ coors, const float* __restrict__ w,
                       short* __restrict__ fb, int* __restrict__ map,
                       short* __restrict__ wt) {
    int b = blockIdx.x;
    if (b < FEAT_BLOCKS) {
        int t = b * 256 + threadIdx.x;                // t < N*8
        int n = t >> 3, seg = t & 7;
        const float* src = (seg < 4) ? (xf + n*32 + seg*8) : (hf + n*32 + seg*8 - 32);
        float4 a = ((const float4*)src)[0];
        float4 bb = ((const float4*)src)[1];
        bf8 rv;
        rv[0]=f2bf(a.x); rv[1]=f2bf(a.y); rv[2]=f2bf(a.z); rv[3]=f2bf(a.w);
        rv[4]=f2bf(bb.x); rv[5]=f2bf(bb.y); rv[6]=f2bf(bb.z); rv[7]=f2bf(bb.w);
        ((bf8*)fb)[(n+1)*8 + seg] = rv;               // row n+1 (row 0 = zeros)
        if (seg == 0) {
            int4 c = ((const int4*)coors)[n];
            int mb = ((c.x*MD + c.y+1)*MH + c.z+1)*MW + (c.w+1);
            map[mb] = n + 1;                          // 0 = empty
        }
    } else {
        int t = (b - FEAT_BLOCKS) * 256 + threadIdx.x;
        if (t < 27*64*128) {
            int jj = t & 7, c = (t >> 3) & 127, jg = (t >> 10) & 7, k = t >> 13;
            int j = jg*8 + jj;
            wt[t] = f2bf(w[(k*64 + j)*128 + c]);      // Wt[k][jg][c][jj] = W[k][j][c]
        }
    }
}

__launch_bounds__(256, 2)
__global__ void k_main(const int* __restrict__ map, const short* __restrict__ fb,
                       const short* __restrict__ wt, const float* __restrict__ bias,
                       const float* __restrict__ cfeat, const int* __restrict__ coors,
                       float* __restrict__ out)
{
    __shared__ short Wlds[3][8192];   // triple-buffered W slice: 3 x 16 kB

    const int tid  = threadIdx.x;
    const int lane = tid & 63;
    const int wv   = tid >> 6;
    const int l31  = lane & 31;
    const int lhi  = lane >> 5;

    const int pbase = blockIdx.x * 256;
    const int p     = pbase + wv*64 + lane;

    const int4 cr = ((const int4*)coors)[p];   // b,z,y,x
    const int mb = ((cr.x*MD + cr.y+1)*MH + cr.z+1)*MW + (cr.w+1);

    // probe: ONE unconditional load. Halo + zero-init make bounds checks free.
    auto probe = [&](int ko) -> int { return map[mb + DOFF[ko]]; };

    // async stage of W[ko] (16 kB) into Wlds[ko%3]; exactly 4 vmem ops per wave
    auto stageW = [&](int ko) {
        const short* src = wt + ko*8192;
        short* dst = &Wlds[ko % 3][0];
        #pragma unroll
        for (int i = 0; i < 4; i++) {
            int cb = i*256 + wv*64;          // 16B-chunk base for this wave
            __builtin_amdgcn_global_load_lds(
                (const __attribute__((address_space(1))) void*)(src + (size_t)(cb + lane)*8),
                (__attribute__((address_space(3))) void*)(dst + (size_t)cb*8),
                16, 0, 0);
        }
    };

    // register gather: row v (v==0 -> zero row). Exactly 8 vmem ops, no selects.
    auto gather = [&](int v0, int v1, bf8* dst) {
        const short* s0 = fb + (size_t)v0*64 + lhi*8;
        const short* s1 = fb + (size_t)v1*64 + lhi*8;
        #pragma unroll
        for (int j = 0; j < 4; j++) {
            dst[j]     = *(const bf8*)(s0 + j*16);
            dst[4 + j] = *(const bf8*)(s1 + j*16);
        }
    };

    f16v acc[2][4];
    #pragma unroll
    for (int mt = 0; mt < 2; mt++)
        #pragma unroll
        for (int ct = 0; ct < 4; ct++) {
            float bv = bias[ct*32 + l31];
            #pragma unroll
            for (int r = 0; r < 16; r++) acc[mt][ct][r] = bv;
        }

    // ---- prologue: W(0), W(1); probes 0..2; first gather into fA ----
    stageW(0);
    stageW(1);
    __builtin_amdgcn_sched_barrier(0);   // keep the 8 stage DMAs oldest
    int pA = probe(0);
    int pB = probe(1);
    int pr_old = probe(2);

    bf8 fA[8], fB[8];
    gather(__shfl(pA, l31, 64), __shfl(pA, l31 + 32, 64), fA);
    int g0n = __shfl(pB, l31, 64);
    int g1n = __shfl(pB, l31 + 32, 64);

    __builtin_amdgcn_sched_barrier(0);
    asm volatile("s_waitcnt vmcnt(11)" ::: "memory");   // both W bufs landed
    __builtin_amdgcn_s_barrier();
    __builtin_amdgcn_sched_barrier(0);

    // Iter ko: MFMA consumes FA (gathered last iter) from Wlds[ko%3] (staged 2 iters ago);
    // stages W[ko+2]; gathers FB for next iter. Counted vmcnt: stage DMAs get ~2 iters
    // of latency cover; gathers + probe always stay in flight across the barrier.
#define ITER_BODY(KO, FA, FB)                                                     \
    {                                                                             \
        const int _ko = (KO);                                                     \
        if (_ko < 25) stageW(_ko + 2);          /* 4 vmem DMAs, oldest this iter */\
        __builtin_amdgcn_sched_barrier(0);                                        \
        if (_ko < 26) gather(g0n, g1n, FB);     /* 8 vmem, consumed next iter */  \
        int pr_new = (_ko < 24) ? probe(_ko + 3) : 0;   /* 1 vmem */              \
        const short* wbuf = &Wlds[_ko % 3][0];                                    \
        _Pragma("unroll")                                                         \
        for (int ks = 0; ks < 4; ks++) {                                          \
            int jg = ks*2 + lhi;                                                  \
            const short* wb = wbuf + (jg*128 + l31)*8;                            \
            _Pragma("unroll")                                                     \
            for (int ct = 0; ct < 4; ct++) {                                      \
                bf8 b = *(const bf8*)(wb + ct*32*8);                              \
                acc[0][ct] = __builtin_amdgcn_mfma_f32_32x32x16_bf16(FA[ks],     b, acc[0][ct], 0, 0, 0); \
                acc[1][ct] = __builtin_amdgcn_mfma_f32_32x32x16_bf16(FA[4 + ks], b, acc[1][ct], 0, 0, 0); \
            }                                                                     \
        }                                                                         \
        if (_ko < 25) {                         /* ids for offset ko+2 */         \
            g0n = __shfl(pr_old, l31, 64);                                        \
            g1n = __shfl(pr_old, l31 + 32, 64);                                   \
            pr_old = pr_new;                                                      \
        }                                                                         \
        if (_ko < 26) {                                                           \
            __builtin_amdgcn_sched_barrier(0);                                    \
            /* ensure W staged LAST iter landed; newer g/p/stage ops keep flying */\
            if (_ko < 24)       { asm volatile("s_waitcnt vmcnt(22)" ::: "memory"); } \
            else if (_ko == 24) { asm volatile("s_waitcnt vmcnt(21)" ::: "memory"); } \
            else                { asm volatile("s_waitcnt vmcnt(16)" ::: "memory"); } \
            __builtin_amdgcn_s_barrier();                                         \
            __builtin_amdgcn_sched_barrier(0);                                    \
        }                                                                         \
    }

    #pragma unroll 1
    for (int ko = 0; ko < 26; ko += 2) {
        ITER_BODY(ko,     fA, fB)
        ITER_BODY(ko + 1, fB, fA)
    }
    ITER_BODY(26, fA, fB)
#undef ITER_BODY

    // ---- epilogue: LSTM gates, lane-local; original order -> coalesced ----
    #pragma unroll
    for (int mt = 0; mt < 2; mt++) {
        #pragma unroll
        for (int r = 0; r < 16; r++) {
            int row = (r & 3) + 8*(r >> 2) + 4*lhi;
            int pp  = pbase + wv*64 + mt*32 + row;
            float gi = acc[mt][0][r];
            float gf = acc[mt][1][r];
            float go = acc[mt][2][r];
            float gg = acc[mt][3][r];
            float cv = cfeat[pp*32 + l31];
            float si = fast_sigmoid(gi);
            float sf = fast_sigmoid(gf);
            float so = fast_sigmoid(go);
            float tg = fast_tanh(gg);
            float cn = sf*cv + si*tg;
            float hn = so * fast_tanh(cn);
            out[pp*32 + l31] = hn;
            out[N_PTS*32 + pp*32 + l31] = cn;
        }
    }
}

extern "C" void kernel_launch(void* const* d_in, const int* in_sizes, int n_in,
                              void* d_out, int out_size, void* d_ws, size_t ws_size,
                              hipStream_t stream) {
    const float* xf    = (const float*)d_in[0];
    const float* hf    = (const float*)d_in[1];
    const float* cf    = (const float*)d_in[2];
    const float* w     = (const float*)d_in[3];
    const float* bias  = (const float*)d_in[4];
    const int*   coors = (const int*)d_in[5];
    float* out = (float*)d_out;

    char* base = (char*)d_ws;
    int*   map    = (int*)base;                       // 35,145,792 B (padded MAP_PAD)
    short* fb     = (short*)(base + MAP_PAD);         // (N_PTS+1)*128 = 67,108,992 B
    short* wtb    = (short*)(base + MAP_PAD + (size_t)(N_PTS+1)*128);  // 442,368 B

    // one memset zeroes the halo map AND fb's zero row (adjacent, 128B-aligned)
    hipMemsetAsync(base, 0, MAP_PAD + 128, stream);
    k_prep<<<FEAT_BLOCKS + WT_BLOCKS, 256, 0, stream>>>(xf, hf, coors, w, fb, map, wtb);
    k_main<<<N_PTS/256, 256, 0, stream>>>(map, fb, wtb, bias, cf, coors, out);
}